// Round 1
// baseline (18720.012 us; speedup 1.0000x reference)
//
// LSTM trajectory autoencoder, MI355X gfx950.
// R1: correctness-first. One workgroup per 16-row batch tile runs the whole
// encoder + decoder recurrence in-kernel (no grid sync). Weights bf16,
// pre-packed into exact MFMA B-fragment stream order (reused by future
// LDS/VGPR-resident versions). FAST path precomputes xe = leaky(x@Wip+b)@Wi_e+b_e
// (needs ~676MB ws); SLOW fallback computes everything in-loop (~2.2MB ws).
#include <hip/hip_runtime.h>

typedef unsigned short u16;
typedef float f32x4 __attribute__((ext_vector_type(4)));
typedef __bf16 bf16x8 __attribute__((ext_vector_type(8)));

#define NBATCH 512
#define NT_ 512
#define NOBS 64
#define NH 256
#define NG4 1024

__device__ __forceinline__ u16 f2bf(float f) {
  unsigned u = __builtin_bit_cast(unsigned, f);
  u += 0x7FFFu + ((u >> 16) & 1u);
  return (u16)(u >> 16);
}
__device__ __forceinline__ float bf2f(u16 h) {
  unsigned u = ((unsigned)h) << 16;
  return __builtin_bit_cast(float, u);
}
__device__ __forceinline__ f32x4 splat4(float b) { f32x4 v = {b, b, b, b}; return v; }
__device__ __forceinline__ bf16x8 asb(uint4 v) { return __builtin_bit_cast(bf16x8, v); }
__device__ __forceinline__ float sigf(float v) { return 1.0f / (1.0f + exp2f(-1.44269504f * v)); }
__device__ __forceinline__ float tanhf_(float v) { float e = exp2f(2.88539008f * v); return 1.0f - 2.0f / (e + 1.0f); }

// ---------------- weight packing -------------------------------------------
// Fragment stream for the z-GEMM ([16,256]@[256,1024], mfma 16x16x32 bf16).
// frag index = w*64 + ks*8 + nt  (w: wave 0..7, ks: K-step 0..7, nt: N-tile 0..7)
// lane l holds 8 bf16: W[k = ks*32 + (l>>4)*8 + j][col], col = (nt>>1)*256 + w*32 + (nt&1)*16 + (l&15)
__global__ void k_pack_gate(const float* __restrict__ src, const float* __restrict__ src2,
                            u16* __restrict__ dst) {
  int e = blockIdx.x * 256 + threadIdx.x;      // 262144 elements
  int frag = e >> 9, lane = (e >> 3) & 63, j = e & 7;
  int w = frag >> 6, ks = (frag >> 3) & 7, nt = frag & 7;
  int k = ks * 32 + ((lane >> 4) << 3) + j;
  int col = ((nt >> 1) << 8) + (w << 5) + ((nt & 1) << 4) + (lane & 15);
  float v = src[k * NG4 + col];
  if (src2) v += src2[k * NG4 + col];
  dst[e] = f2bf(v);
}

// Wip [64,256] frags for in-loop xp (SLOW path). frag = w*4 + ks2*2 + cg
__global__ void k_pack_wip(const float* __restrict__ Wip, u16* __restrict__ dst) {
  int e = blockIdx.x * 256 + threadIdx.x;      // 16384 elements
  int frag = e >> 9, lane = (e >> 3) & 63, j = e & 7;
  int w = frag >> 2, ks2 = (frag >> 1) & 1, cg = frag & 1;
  int k = ks2 * 32 + ((lane >> 4) << 3) + j;
  int col = (w << 5) + (cg << 4) + (lane & 15);
  dst[e] = f2bf(Wip[k * NH + col]);
}

// Wop [256,64] frags (decoder pred). frag = w*8 + ks, w in 0..3
__global__ void k_pack_wop(const float* __restrict__ Wop, u16* __restrict__ dst) {
  int e = blockIdx.x * 256 + threadIdx.x;      // 16384 elements
  int frag = e >> 9, lane = (e >> 3) & 63, j = e & 7;
  int w = frag >> 3, ks = frag & 7;
  int k = ks * 32 + ((lane >> 4) << 3) + j;
  int col = (w << 4) + (lane & 15);
  dst[e] = f2bf(Wop[k * NOBS + col]);
}

// Wi_e transposed [1024][256] bf16 for the xe GEMM's B staging
__global__ void k_transpose_wie(const float* __restrict__ Wie, u16* __restrict__ wieT) {
  int e = blockIdx.x * 256 + threadIdx.x;      // 262144
  int n = e >> 8, k = e & 255;
  wieT[n * NH + k] = f2bf(Wie[k * NG4 + n]);
}

// lengths from mask; auto-detect uint8-bool vs int32 storage.
__global__ void k_lens(const unsigned char* __restrict__ mask, int* __restrict__ lens) {
  int b = threadIdx.x;                          // 512 threads, 1 block
  bool u8 = (mask[1] | mask[2] | mask[3]) != 0; // row0 t=1..3 are true (len>=128)
  int s = 0;
  if (u8) {
    const unsigned char* row = mask + b * NT_;
    for (int t = 0; t < NT_; t++) s += row[t] ? 1 : 0;
  } else {
    const int* row = (const int*)mask + b * NT_;
    for (int t = 0; t < NT_; t++) s += row[t] ? 1 : 0;
  }
  lens[b] = s;
}

// bitonic sort 512 rows by length (ascending) -> rowmap (original row ids)
__global__ void k_sort(const int* __restrict__ lens, int* __restrict__ rowmap) {
  __shared__ int sk[512];
  int tid = threadIdx.x;
  sk[tid] = lens[tid] * 1024 + tid;
  __syncthreads();
  for (int k = 2; k <= 512; k <<= 1)
    for (int j = k >> 1; j > 0; j >>= 1) {
      int ixj = tid ^ j;
      if (ixj > tid) {
        int a = sk[tid], b = sk[ixj];
        bool up = ((tid & k) == 0);
        if ((a > b) == up) { sk[tid] = b; sk[ixj] = a; }
      }
      __syncthreads();
    }
  rowmap[tid] = sk[tid] & 1023;
}

// ---------------- xp = leaky(x@Wip + bip) ----------------------------------
__global__ __launch_bounds__(256) void k_xproj(const float* __restrict__ x,
                                               const float* __restrict__ Wip,
                                               const float* __restrict__ bip,
                                               u16* __restrict__ xp) {
  __shared__ float xs[64 * 64];
  int tid = threadIdx.x;
  int r0 = blockIdx.x * 64;
  for (int i = tid; i < 4096; i += 256) xs[i] = x[r0 * 64 + i];
  __syncthreads();
  float wcol[64];
#pragma unroll
  for (int k = 0; k < 64; k++) wcol[k] = Wip[k * NH + tid];
  float bv = bip[tid];
  for (int r = 0; r < 64; r++) {
    float a = bv;
#pragma unroll
    for (int k = 0; k < 64; k++) a = fmaf(xs[r * 64 + k], wcol[k], a);
    a = a >= 0.f ? a : 0.01f * a;
    xp[(r0 + r) * NH + tid] = f2bf(a);
  }
}

// ---------------- xe = xp @ Wi_e + b_e (bf16 out) --------------------------
__global__ __launch_bounds__(256) void k_xe_gemm(const u16* __restrict__ xp,
                                                 const u16* __restrict__ wieT,
                                                 const float* __restrict__ be,
                                                 u16* __restrict__ xe) {
  __shared__ __align__(16) u16 As[128 * 40];
  __shared__ __align__(16) u16 Bs[128 * 40];
  int tid = threadIdx.x, w = tid >> 6, lane = tid & 63, q = lane >> 4, n16 = lane & 15;
  int m0 = blockIdx.x * 128, ncol0 = blockIdx.y * 128;
  int wm = (w >> 1) * 64, wn = (w & 1) * 64;
  f32x4 acc[4][4];
#pragma unroll
  for (int a = 0; a < 4; a++)
#pragma unroll
    for (int b = 0; b < 4; b++) acc[a][b] = splat4(0.f);
  int sr = tid >> 1, sh = tid & 1;
  const uint4* asrc = (const uint4*)(xp + (size_t)(m0 + sr) * NH);
  const uint4* bsrc = (const uint4*)(wieT + (size_t)(ncol0 + sr) * NH);
  uint4* adst = (uint4*)&As[sr * 40 + sh * 16];
  uint4* bdst = (uint4*)&Bs[sr * 40 + sh * 16];
  for (int kc = 0; kc < 8; kc++) {
    uint4 a0 = asrc[kc * 4 + sh * 2], a1 = asrc[kc * 4 + sh * 2 + 1];
    uint4 b0 = bsrc[kc * 4 + sh * 2], b1 = bsrc[kc * 4 + sh * 2 + 1];
    __syncthreads();   // previous iter's frag reads done
    adst[0] = a0; adst[1] = a1; bdst[0] = b0; bdst[1] = b1;
    __syncthreads();
    bf16x8 af[4], bfr[4];
#pragma unroll
    for (int s = 0; s < 4; s++) {
      af[s]  = *(const bf16x8*)&As[(wm + s * 16 + n16) * 40 + q * 8];
      bfr[s] = *(const bf16x8*)&Bs[(wn + s * 16 + n16) * 40 + q * 8];
    }
#pragma unroll
    for (int sm = 0; sm < 4; sm++)
#pragma unroll
      for (int sn = 0; sn < 4; sn++)
        acc[sm][sn] = __builtin_amdgcn_mfma_f32_16x16x32_bf16(af[sm], bfr[sn], acc[sm][sn], 0, 0, 0);
  }
#pragma unroll
  for (int sm = 0; sm < 4; sm++)
#pragma unroll
    for (int sn = 0; sn < 4; sn++)
#pragma unroll
      for (int r = 0; r < 4; r++) {
        int row = m0 + wm + sm * 16 + q * 4 + r;
        int col = ncol0 + wn + sn * 16 + n16;
        xe[(size_t)row * NG4 + col] = f2bf(acc[sm][sn][r] + be[col]);
      }
}

// ---------------- the recurrent kernel -------------------------------------
// 32 blocks x 512 threads. Block = 16 batch rows (via rowmap). Wave w owns
// h-cols [w*32, w*32+32). c in fp32 regs; h in LDS bf16 (A-frag layout).
template <bool PRECOMP>
__global__ __launch_bounds__(512) void k_recurrent(
    const float* __restrict__ x, const u16* __restrict__ xe,
    const u16* __restrict__ whe_s, const u16* __restrict__ wie_s,
    const u16* __restrict__ wd_s, const u16* __restrict__ wip_s,
    const u16* __restrict__ wop_s,
    const float* __restrict__ bip, const float* __restrict__ be,
    const float* __restrict__ Wlp, const float* __restrict__ blp,
    const float* __restrict__ Wle, const float* __restrict__ ble,
    const float* __restrict__ bd, const float* __restrict__ bop,
    const int* __restrict__ lens, const int* __restrict__ rowmap,
    float* __restrict__ out) {
  constexpr int LD = PRECOMP ? 264 : 520;   // +8 el pad: keeps 16B align, spreads banks
  constexpr int HOFF = PRECOMP ? 0 : 256;   // h column offset inside hx
  __shared__ __align__(16) u16 hx[16 * LD];
  __shared__ __align__(16) u16 xbuf[16 * 72];
  __shared__ int ob_s[16], len_s[16];
  __shared__ float lat_s[256];

  const int tid = threadIdx.x;
  const int w = tid >> 6, lane = tid & 63, q = lane >> 4, n16 = lane & 15;
  const int tile = blockIdx.x;

  if (tid < 16) {
    int ob = rowmap[tile * 16 + tid];
    ob_s[tid] = ob;
    len_s[tid] = lens[ob];
  }
  for (int i = tid; i < 16 * LD; i += 512) hx[i] = 0;
  __syncthreads();

  int maxlen = 0;
#pragma unroll
  for (int i = 0; i < 16; i++) maxlen = len_s[i] > maxlen ? len_s[i] : maxlen;

  int myrow[4], mylen[4], xebase[4], orow[4];
#pragma unroll
  for (int r = 0; r < 4; r++) {
    myrow[r] = ob_s[q * 4 + r];
    mylen[r] = len_s[q * 4 + r];
    xebase[r] = myrow[r] << 19;  // *512*1024
    orow[r] = myrow[r] << 15;    // *512*64
  }
  int zcol[8];
#pragma unroll
  for (int nt = 0; nt < 8; nt++)
    zcol[nt] = ((nt >> 1) << 8) + (w << 5) + ((nt & 1) << 4) + n16;

  const uint4* whe4 = (const uint4*)whe_s;
  const uint4* wie4 = (const uint4*)wie_s;
  const uint4* wd4 = (const uint4*)wd_s;
  const int fb = w * 64;  // this wave's frag base

  uint4 wipf[4];
  float bip_r[2], be_r[8];
  if constexpr (!PRECOMP) {
    const uint4* wip4 = (const uint4*)wip_s;
#pragma unroll
    for (int i = 0; i < 4; i++) wipf[i] = wip4[(w * 4 + i) * 64 + lane];
    bip_r[0] = bip[(w << 5) + n16];
    bip_r[1] = bip[(w << 5) + 16 + n16];
#pragma unroll
    for (int nt = 0; nt < 8; nt++) be_r[nt] = be[zcol[nt]];
  }

  float creg[4][2];
#pragma unroll
  for (int r = 0; r < 4; r++) { creg[r][0] = 0.f; creg[r][1] = 0.f; }

  const char* hxb = (const char*)hx;

  // ================= encoder =================
  for (int t = 0; t < maxlen; t++) {
    f32x4 acc[8];
    if constexpr (PRECOMP) {
#pragma unroll
      for (int nt = 0; nt < 8; nt++)
#pragma unroll
        for (int r = 0; r < 4; r++)
          acc[nt][r] = bf2f(xe[xebase[r] + (t << 10) + zcol[nt]]);
    } else {
      // stage x_t -> xbuf (bf16)
      for (int i = tid; i < 1024; i += 512) {
        int m = i >> 6, k = i & 63;
        xbuf[m * 72 + k] = f2bf(x[(ob_s[m] * NT_ + t) * NOBS + k]);
      }
      __syncthreads();
      f32x4 xacc[2];
#pragma unroll
      for (int cg = 0; cg < 2; cg++) xacc[cg] = splat4(bip_r[cg]);
#pragma unroll
      for (int ks2 = 0; ks2 < 2; ks2++) {
        bf16x8 a = *(const bf16x8*)((const char*)xbuf + n16 * 144 + ks2 * 64 + q * 16);
#pragma unroll
        for (int cg = 0; cg < 2; cg++)
          xacc[cg] = __builtin_amdgcn_mfma_f32_16x16x32_bf16(a, asb(wipf[ks2 * 2 + cg]), xacc[cg], 0, 0, 0);
      }
#pragma unroll
      for (int r = 0; r < 4; r++)
#pragma unroll
        for (int cg = 0; cg < 2; cg++) {
          float v = xacc[cg][r];
          v = v >= 0.f ? v : 0.01f * v;
          hx[(q * 4 + r) * LD + (w << 5) + (cg << 4) + n16] = f2bf(v);
        }
      __syncthreads();   // xp region visible
#pragma unroll
      for (int nt = 0; nt < 8; nt++) acc[nt] = splat4(be_r[nt]);
    }
    // z-GEMM
    constexpr int KS = PRECOMP ? 8 : 16;
#pragma unroll
    for (int ks = 0; ks < KS; ks++) {
      bf16x8 a = *(const bf16x8*)(hxb + n16 * (LD * 2) + ks * 64 + q * 16);
      const uint4* bp;
      int kk;
      if constexpr (PRECOMP) { bp = whe4; kk = ks; }
      else { bp = (ks < 8) ? wie4 : whe4; kk = ks & 7; }
#pragma unroll
      for (int nt = 0; nt < 8; nt++)
        acc[nt] = __builtin_amdgcn_mfma_f32_16x16x32_bf16(a, asb(bp[(fb + kk * 8 + nt) * 64 + lane]), acc[nt], 0, 0, 0);
    }
    // LSTM update (gates order i,f,g,o)
    float nh_s[4][2];
#pragma unroll
    for (int r = 0; r < 4; r++) {
      bool upd = t < mylen[r];
#pragma unroll
      for (int cg = 0; cg < 2; cg++) {
        float i_ = sigf(acc[cg][r]);
        float f_ = sigf(acc[2 + cg][r]);
        float g_ = tanhf_(acc[4 + cg][r]);
        float o_ = sigf(acc[6 + cg][r]);
        float nc = f_ * creg[r][cg] + i_ * g_;
        float nh = o_ * tanhf_(nc);
        if (upd) creg[r][cg] = nc;
        nh_s[r][cg] = nh;
      }
    }
    __syncthreads();   // everyone done reading h_t
#pragma unroll
    for (int r = 0; r < 4; r++)
      if (t < mylen[r]) {
#pragma unroll
        for (int cg = 0; cg < 2; cg++)
          hx[(q * 4 + r) * LD + HOFF + (w << 5) + (cg << 4) + n16] = f2bf(nh_s[r][cg]);
      }
    __syncthreads();   // h_{t+1} visible
  }

  // ================= latent + ctx =================
  if (tid < 256) {
    int m = tid >> 4, j = tid & 15;
    float s = blp[j];
    for (int k = 0; k < NH; k++) s = fmaf(bf2f(hx[m * LD + HOFF + k]), Wlp[k * 16 + j], s);
    out[16777216 + ob_s[m] * 16 + j] = s;
    lat_s[m * 16 + j] = s;
  }
  __syncthreads();
  for (int i = tid; i < 4096; i += 512) {
    int m = i >> 8, cc = i & 255;
    float s = ble[cc];
#pragma unroll
    for (int k = 0; k < 16; k++) s = fmaf(lat_s[m * 16 + k], Wle[k * NH + cc], s);
    s = s >= 0.f ? s : 0.01f * s;
    hx[m * LD + HOFF + cc] = f2bf(s);
  }
  __syncthreads();

  // ================= decoder =================
#pragma unroll
  for (int r = 0; r < 4; r++)
#pragma unroll
    for (int cg = 0; cg < 2; cg++)
      creg[r][cg] = bf2f(hx[(q * 4 + r) * LD + HOFF + (w << 5) + (cg << 4) + n16]);

  uint4 wopf[8];
  float bop_r = 0.f;
  if (w < 4) {
    const uint4* wop4 = (const uint4*)wop_s;
#pragma unroll
    for (int ks = 0; ks < 8; ks++) wopf[ks] = wop4[(w * 8 + ks) * 64 + lane];
    bop_r = bop[(w << 4) + n16];
  }
  float bd_r[8];
#pragma unroll
  for (int nt = 0; nt < 8; nt++) bd_r[nt] = bd[zcol[nt]];

  for (int t = 0; t < NT_; t++) {
    f32x4 acc[8];
#pragma unroll
    for (int nt = 0; nt < 8; nt++) acc[nt] = splat4(bd_r[nt]);
    f32x4 pacc = splat4(0.f);
#pragma unroll
    for (int ks = 0; ks < 8; ks++) {
      bf16x8 a = *(const bf16x8*)(hxb + n16 * (LD * 2) + HOFF * 2 + ks * 64 + q * 16);
      if (w < 4) pacc = __builtin_amdgcn_mfma_f32_16x16x32_bf16(a, asb(wopf[ks]), pacc, 0, 0, 0);
#pragma unroll
      for (int nt = 0; nt < 8; nt++)
        acc[nt] = __builtin_amdgcn_mfma_f32_16x16x32_bf16(a, asb(wd4[(fb + ks * 8 + nt) * 64 + lane]), acc[nt], 0, 0, 0);
    }
    // pred from h_t belongs to recon[:, t-1]
    if (w < 4 && t > 0) {
#pragma unroll
      for (int r = 0; r < 4; r++)
        out[orow[r] + ((t - 1) << 6) + (w << 4) + n16] = pacc[r] + bop_r;
    }
    float nh_s[4][2];
#pragma unroll
    for (int r = 0; r < 4; r++)
#pragma unroll
      for (int cg = 0; cg < 2; cg++) {
        float i_ = sigf(acc[cg][r]);
        float f_ = sigf(acc[2 + cg][r]);
        float g_ = tanhf_(acc[4 + cg][r]);
        float o_ = sigf(acc[6 + cg][r]);
        float nc = f_ * creg[r][cg] + i_ * g_;
        creg[r][cg] = nc;
        nh_s[r][cg] = o_ * tanhf_(nc);
      }
    __syncthreads();
#pragma unroll
    for (int r = 0; r < 4; r++)
#pragma unroll
      for (int cg = 0; cg < 2; cg++)
        hx[(q * 4 + r) * LD + HOFF + (w << 5) + (cg << 4) + n16] = f2bf(nh_s[r][cg]);
    __syncthreads();
  }
  // final pred from h_512 -> recon[:, 511]
  if (w < 4) {
    f32x4 pacc = splat4(0.f);
#pragma unroll
    for (int ks = 0; ks < 8; ks++) {
      bf16x8 a = *(const bf16x8*)(hxb + n16 * (LD * 2) + HOFF * 2 + ks * 64 + q * 16);
      pacc = __builtin_amdgcn_mfma_f32_16x16x32_bf16(a, asb(wopf[ks]), pacc, 0, 0, 0);
    }
#pragma unroll
    for (int r = 0; r < 4; r++)
      out[orow[r] + (511 << 6) + (w << 4) + n16] = pacc[r] + bop_r;
  }
}

// ---------------- host ------------------------------------------------------
#define OFF_WHE 0ull
#define OFF_WD 524288ull
#define OFF_WIE 1048576ull
#define OFF_WIET 1572864ull
#define OFF_WIP 2097152ull
#define OFF_WOP 2129920ull
#define OFF_LENS 2162688ull
#define OFF_ROWMAP 2164736ull
#define MIN_WS 2166784ull
#define OFF_XP 4194304ull
#define OFF_XE 138412032ull
#define NEED_FAST 675282944ull

extern "C" void kernel_launch(void* const* d_in, const int* in_sizes, int n_in,
                              void* d_out, int out_size, void* d_ws, size_t ws_size,
                              hipStream_t stream) {
  const float* x = (const float*)d_in[0];
  const unsigned char* mask = (const unsigned char*)d_in[1];
  const float* Wip = (const float*)d_in[2];
  const float* bip = (const float*)d_in[3];
  const float* Wie = (const float*)d_in[4];
  const float* Whe = (const float*)d_in[5];
  const float* be = (const float*)d_in[6];
  const float* Wlp = (const float*)d_in[7];
  const float* blp = (const float*)d_in[8];
  const float* Wle = (const float*)d_in[9];
  const float* ble = (const float*)d_in[10];
  const float* Wid = (const float*)d_in[11];
  const float* Whd = (const float*)d_in[12];
  const float* bd = (const float*)d_in[13];
  const float* Wop = (const float*)d_in[14];
  const float* bop = (const float*)d_in[15];
  float* out = (float*)d_out;
  char* ws = (char*)d_ws;

  if (ws_size < MIN_WS) return;  // cannot operate without minimal scratch

  u16* whe_s = (u16*)(ws + OFF_WHE);
  u16* wd_s = (u16*)(ws + OFF_WD);
  u16* wie_s = (u16*)(ws + OFF_WIE);
  u16* wieT = (u16*)(ws + OFF_WIET);
  u16* wip_s = (u16*)(ws + OFF_WIP);
  u16* wop_s = (u16*)(ws + OFF_WOP);
  int* lens = (int*)(ws + OFF_LENS);
  int* rowmap = (int*)(ws + OFF_ROWMAP);
  u16* xp = (u16*)(ws + OFF_XP);
  u16* xe = (u16*)(ws + OFF_XE);

  bool fast = ws_size >= NEED_FAST;

  k_pack_gate<<<1024, 256, 0, stream>>>(Whe, nullptr, whe_s);
  k_pack_gate<<<1024, 256, 0, stream>>>(Wie, nullptr, wie_s);
  k_pack_gate<<<1024, 256, 0, stream>>>(Wid, Whd, wd_s);
  k_pack_wip<<<64, 256, 0, stream>>>(Wip, wip_s);
  k_pack_wop<<<64, 256, 0, stream>>>(Wop, wop_s);
  k_transpose_wie<<<1024, 256, 0, stream>>>(Wie, wieT);
  k_lens<<<1, 512, 0, stream>>>(mask, lens);
  k_sort<<<1, 512, 0, stream>>>(lens, rowmap);

  if (fast) {
    k_xproj<<<4096, 256, 0, stream>>>(x, Wip, bip, xp);
    k_xe_gemm<<<dim3(2048, 8), 256, 0, stream>>>(xp, wieT, be, xe);
    k_recurrent<true><<<32, 512, 0, stream>>>(x, xe, whe_s, wie_s, wd_s, wip_s, wop_s,
                                              bip, be, Wlp, blp, Wle, ble, bd, bop,
                                              lens, rowmap, out);
  } else {
    k_recurrent<false><<<32, 512, 0, stream>>>(x, (const u16*)ws, whe_s, wie_s, wd_s, wip_s, wop_s,
                                               bip, be, Wlp, blp, Wle, ble, bd, bop,
                                               lens, rowmap, out);
  }
}

// Round 3
// 10728.953 us; speedup vs baseline: 1.7448x; 1.7448x over previous
//
// LSTM trajectory autoencoder, MI355X gfx950 — R3: persistent-RNN, fixed ws map.
// R2 bug: hpub (needs 512KB) overflowed into eflag/dflag/lens/rowmap -> flag
// corruption -> stale h / spin timeouts. R3: correct layout; lens+rowmap merged
// into skeys (len*1024|row) to keep MIN_WS under the proven-available 2166784.
// Sync protocol unchanged (verified: producer can't overwrite a parity buffer
// until all consumers finished the step that read it).
#include <hip/hip_runtime.h>

typedef unsigned short u16;
typedef unsigned long long u64;
typedef float f32x4 __attribute__((ext_vector_type(4)));
typedef __bf16 bf16x8 __attribute__((ext_vector_type(8)));

#define NT_ 512
#define LD 264   // 16 rows x 264 u16 (8-el pad)

__device__ __forceinline__ u16 f2bf(float f) {
  unsigned u = __builtin_bit_cast(unsigned, f);
  u += 0x7FFFu + ((u >> 16) & 1u);
  return (u16)(u >> 16);
}
__device__ __forceinline__ float bf2f(u16 h) {
  unsigned u = ((unsigned)h) << 16;
  return __builtin_bit_cast(float, u);
}
__device__ __forceinline__ f32x4 splat4(float b) { f32x4 v = {b, b, b, b}; return v; }
__device__ __forceinline__ bf16x8 asb(uint4 v) { return __builtin_bit_cast(bf16x8, v); }
__device__ __forceinline__ float sigf(float v) { return 1.0f / (1.0f + exp2f(-1.44269504f * v)); }
__device__ __forceinline__ float tanhf_(float v) { float e = exp2f(2.88539008f * v); return 1.0f - 2.0f / (e + 1.0f); }

// ---------------- packing ---------------------------------------------------
// gate-weight frag stream: bits  s[17:16] w[15:14] ks[13:11] g[10:9] lane[8:3] j[2:0]
// lane holds W[k=ks*32+(lane>>4)*8+j][col=g*256+s*64+w*16+(lane&15)]
__global__ void k_pack_g(const float* __restrict__ src, const float* __restrict__ src2,
                         u16* __restrict__ dst) {
  int e = blockIdx.x * 256 + threadIdx.x;  // 262144
  int j = e & 7, lane = (e >> 3) & 63, g = (e >> 9) & 3, ks = (e >> 11) & 7;
  int w = (e >> 14) & 3, s = (e >> 16) & 3;
  int k = ks * 32 + ((lane >> 4) << 3) + j;
  int col = g * 256 + s * 64 + w * 16 + (lane & 15);
  float v = src[k * 1024 + col];
  if (src2) v += src2[k * 1024 + col];
  dst[e] = f2bf(v);
}
// Wip[64,256]: bits w[13:12] ks2[11] n[10:9] lane[8:3] j[2:0]
__global__ void k_pack_wip(const float* __restrict__ Wip, u16* __restrict__ dst) {
  int e = blockIdx.x * 256 + threadIdx.x;  // 16384
  int j = e & 7, lane = (e >> 3) & 63, n = (e >> 9) & 3, ks2 = (e >> 11) & 1, w = (e >> 12) & 3;
  int k = ks2 * 32 + ((lane >> 4) << 3) + j;
  int col = w * 64 + n * 16 + (lane & 15);
  dst[e] = f2bf(Wip[k * 256 + col]);
}
// Wop[256,64]: bits s[13:12] ks[11:9] lane[8:3] j[2:0]; col = s*16+lane15
__global__ void k_pack_wop(const float* __restrict__ Wop, u16* __restrict__ dst) {
  int e = blockIdx.x * 256 + threadIdx.x;  // 16384
  int j = e & 7, lane = (e >> 3) & 63, ks = (e >> 9) & 7, s = (e >> 12) & 3;
  int k = ks * 32 + ((lane >> 4) << 3) + j;
  int col = s * 16 + (lane & 15);
  dst[e] = f2bf(Wop[k * 64 + col]);
}

// skeys[b] = len(b)*1024 + b   (mask stored as u8-bool or int32 -> autodetect)
__global__ void k_lens(const unsigned char* __restrict__ mask, int* __restrict__ skeys) {
  int b = threadIdx.x;
  bool u8 = (mask[1] | mask[2] | mask[3]) != 0;
  int s = 0;
  if (u8) { const unsigned char* row = mask + b * NT_; for (int t = 0; t < NT_; t++) s += row[t] ? 1 : 0; }
  else { const int* row = (const int*)mask + b * NT_; for (int t = 0; t < NT_; t++) s += row[t] ? 1 : 0; }
  skeys[b] = s * 1024 + b;
}

// in-place ascending bitonic sort of skeys[512]
__global__ void k_sort(int* __restrict__ skeys) {
  __shared__ int sk[512];
  int tid = threadIdx.x;
  sk[tid] = skeys[tid];
  __syncthreads();
  for (int k = 2; k <= 512; k <<= 1)
    for (int j = k >> 1; j > 0; j >>= 1) {
      int ixj = tid ^ j;
      if (ixj > tid) {
        int a = sk[tid], b = sk[ixj];
        bool up = ((tid & k) == 0);
        if ((a > b) == up) { sk[tid] = b; sk[ixj] = a; }
      }
      __syncthreads();
    }
  skeys[tid] = sk[tid];
}

__global__ void k_zero(int* __restrict__ flags) { flags[threadIdx.x] = 0; }

// ---------------- persistent recurrent kernel ------------------------------
// grid 128 x 256 thr (4 waves, 1 wave/SIMD). block b: tile g=(b&7)+((b>>5)<<3),
// slice s=(b>>3)&3  (stride-8 partners -> same XCD under round-robin heuristic).
// wave w owns h-cols s*64+w*16+[0,16); lane(q,n16) rows q*4+r, col w*16+n16.
__global__ __launch_bounds__(256, 1) void k_rec2(
    const float* __restrict__ x,
    const u16* __restrict__ whe_p, const u16* __restrict__ wie_p,
    const u16* __restrict__ wd_p, const u16* __restrict__ wip_p,
    const u16* __restrict__ wop_p,
    const float* __restrict__ bip, const float* __restrict__ be,
    const float* __restrict__ Wlp, const float* __restrict__ blp,
    const float* __restrict__ Wle, const float* __restrict__ ble,
    const float* __restrict__ bd, const float* __restrict__ bop,
    const int* __restrict__ skeys,
    u64* __restrict__ hpub, int* __restrict__ eflag, int* __restrict__ dflag,
    float* __restrict__ out) {
  __shared__ __align__(16) u16 hx[16 * LD];
  __shared__ __align__(16) u16 xps[16 * LD];
  __shared__ __align__(16) u16 xbuf[16 * 72];
  __shared__ int ob_s[16], len_s[16];
  __shared__ float lat_s[256];

  const int tid = threadIdx.x;
  const int w = tid >> 6, lane = tid & 63, q = lane >> 4, n16 = lane & 15;
  const int b = blockIdx.x;
  const int g = (b & 7) + ((b >> 5) << 3);
  const int s = (b >> 3) & 3;

  if (tid < 16) {
    int v = skeys[g * 16 + tid];
    ob_s[tid] = v & 1023;
    len_s[tid] = v >> 10;
  }
  for (int i = tid; i < 16 * LD; i += 256) hx[i] = 0;
  __syncthreads();
  int maxlen = 0;
#pragma unroll
  for (int i = 0; i < 16; i++) maxlen = len_s[i] > maxlen ? len_s[i] : maxlen;
  int mylen[4];
#pragma unroll
  for (int r = 0; r < 4; r++) mylen[r] = len_s[q * 4 + r];

  // ---- load resident weights ----
  const uint4* whe4 = (const uint4*)whe_p;
  const uint4* wie4 = (const uint4*)wie_p;
  const uint4* wip4 = (const uint4*)wip_p;
  uint4 wfh[32], wfx[32], wipf[8];
#pragma unroll
  for (int f = 0; f < 32; f++) wfh[f] = whe4[((s * 4 + w) * 32 + f) * 64 + lane];
#pragma unroll
  for (int f = 0; f < 32; f++) wfx[f] = wie4[((s * 4 + w) * 32 + f) * 64 + lane];
#pragma unroll
  for (int f = 0; f < 8; f++) wipf[f] = wip4[(w * 8 + f) * 64 + lane];

  float be_r[4], bipr[4];
#pragma unroll
  for (int gt = 0; gt < 4; gt++) be_r[gt] = be[gt * 256 + s * 64 + w * 16 + n16];
#pragma unroll
  for (int n = 0; n < 4; n++) bipr[n] = bip[w * 64 + n * 16 + n16];

  float creg[4];
#pragma unroll
  for (int r = 0; r < 4; r++) creg[r] = 0.f;

  const char* hxb = (const char*)hx;
  const char* xpsb = (const char*)xps;
  u64* hpg = hpub + (u64)g * 2048;  // per tile: 2 parities x 4 slices x 256 u64
  int* efl = eflag + g * 4;
  int* dfl = dflag + g * 4;
  const int xr = tid >> 4, xc = tid & 15;

  // ================= encoder =================
  for (int t = 0; t < maxlen; t++) {
    float4 xv = ((const float4*)x)[((size_t)ob_s[xr] * NT_ + t) * 16 + xc];
    if (t > 0) {
      if (tid < 4 && tid != s) {
        int gdn = 0;
        while (__hip_atomic_load(&efl[tid], __ATOMIC_ACQUIRE, __HIP_MEMORY_SCOPE_AGENT) < t &&
               ++gdn < 300000) {}
      }
      __syncthreads();
      const u64* src = hpg + (u64)(t & 1) * 1024;
#pragma unroll
      for (int e3 = 0; e3 < 3; e3++) {
        int e = e3 * 256 + tid;
        int ss = e >> 8; int sidx = ss + (ss >= s);
        int i = e & 255; int r = i >> 4, c4 = i & 15;
        u64 v = __hip_atomic_load(&src[sidx * 256 + i], __ATOMIC_RELAXED, __HIP_MEMORY_SCOPE_AGENT);
        *(u64*)&hx[r * LD + sidx * 64 + c4 * 4] = v;
      }
    }
    {
      u64 pv = (u64)f2bf(xv.x) | ((u64)f2bf(xv.y) << 16) |
               ((u64)f2bf(xv.z) << 32) | ((u64)f2bf(xv.w) << 48);
      *(u64*)&xbuf[xr * 72 + xc * 4] = pv;
    }
    __syncthreads();  // hx(t) + xbuf ready
    // xp = leaky(x_t @ Wip + bip) ; wave w computes cols [w*64, w*64+64)
    f32x4 xacc[4];
#pragma unroll
    for (int n = 0; n < 4; n++) xacc[n] = splat4(bipr[n]);
#pragma unroll
    for (int ks2 = 0; ks2 < 2; ks2++) {
      bf16x8 a = *(const bf16x8*)((const char*)xbuf + n16 * 144 + ks2 * 64 + q * 16);
#pragma unroll
      for (int n = 0; n < 4; n++)
        xacc[n] = __builtin_amdgcn_mfma_f32_16x16x32_bf16(a, asb(wipf[ks2 * 4 + n]), xacc[n], 0, 0, 0);
    }
#pragma unroll
    for (int n = 0; n < 4; n++)
#pragma unroll
      for (int r = 0; r < 4; r++) {
        float v = xacc[n][r];
        v = v >= 0.f ? v : 0.01f * v;
        xps[(q * 4 + r) * LD + w * 64 + n * 16 + n16] = f2bf(v);
      }
    __syncthreads();  // xps ready
    // z = xp@Wie_s + h@Whe_s + be_s
    f32x4 acc[4];
#pragma unroll
    for (int gt = 0; gt < 4; gt++) acc[gt] = splat4(be_r[gt]);
#pragma unroll
    for (int ks = 0; ks < 8; ks++) {
      bf16x8 a = *(const bf16x8*)(xpsb + n16 * (LD * 2) + ks * 64 + q * 16);
#pragma unroll
      for (int gt = 0; gt < 4; gt++)
        acc[gt] = __builtin_amdgcn_mfma_f32_16x16x32_bf16(a, asb(wfx[ks * 4 + gt]), acc[gt], 0, 0, 0);
    }
#pragma unroll
    for (int ks = 0; ks < 8; ks++) {
      bf16x8 a = *(const bf16x8*)(hxb + n16 * (LD * 2) + ks * 64 + q * 16);
#pragma unroll
      for (int gt = 0; gt < 4; gt++)
        acc[gt] = __builtin_amdgcn_mfma_f32_16x16x32_bf16(a, asb(wfh[ks * 4 + gt]), acc[gt], 0, 0, 0);
    }
    float nh_s[4];
#pragma unroll
    for (int r = 0; r < 4; r++) {
      float i_ = sigf(acc[0][r]);
      float f_ = sigf(acc[1][r]);
      float g_ = tanhf_(acc[2][r]);
      float o_ = sigf(acc[3][r]);
      float nc = f_ * creg[r] + i_ * g_;
      if (t < mylen[r]) creg[r] = nc;
      nh_s[r] = o_ * tanhf_(nc);
    }
    __syncthreads();  // all waves done reading hx
#pragma unroll
    for (int r = 0; r < 4; r++)
      if (t < mylen[r])
        hx[(q * 4 + r) * LD + s * 64 + w * 16 + n16] = f2bf(nh_s[r]);
    __syncthreads();  // own slice final
    {
      u64 v = *(u64*)&hx[xr * LD + s * 64 + xc * 4];
      __hip_atomic_store(&hpg[(u64)((t + 1) & 1) * 1024 + s * 256 + xr * 16 + xc], v,
                         __ATOMIC_RELAXED, __HIP_MEMORY_SCOPE_AGENT);
    }
    __threadfence();
    __syncthreads();
    if (tid == 0) __hip_atomic_fetch_add(&efl[s], 1, __ATOMIC_RELEASE, __HIP_MEMORY_SCOPE_AGENT);
  }

  // final exchange: full h_maxlen
  if (tid < 4 && tid != s) {
    int gdn = 0;
    while (__hip_atomic_load(&efl[tid], __ATOMIC_ACQUIRE, __HIP_MEMORY_SCOPE_AGENT) < maxlen &&
           ++gdn < 300000) {}
  }
  __syncthreads();
  {
    const u64* src = hpg + (u64)(maxlen & 1) * 1024;
#pragma unroll
    for (int e3 = 0; e3 < 3; e3++) {
      int e = e3 * 256 + tid;
      int ss = e >> 8; int sidx = ss + (ss >= s);
      int i = e & 255; int r = i >> 4, c4 = i & 15;
      u64 v = __hip_atomic_load(&src[sidx * 256 + i], __ATOMIC_RELAXED, __HIP_MEMORY_SCOPE_AGENT);
      *(u64*)&hx[r * LD + sidx * 64 + c4 * 4] = v;
    }
  }
  __syncthreads();
  // signal: done reading encoder buffers (decoder ready handshake)
  if (tid == 0) __hip_atomic_fetch_add(&dfl[s], 1, __ATOMIC_RELEASE, __HIP_MEMORY_SCOPE_AGENT);

  // ---- latent (redundant per cluster; slice 0 writes) ----
  {
    int m = tid >> 4, j = tid & 15;
    float acc_ = blp[j];
    for (int k = 0; k < 256; k++) acc_ = fmaf(bf2f(hx[m * LD + k]), Wlp[k * 16 + j], acc_);
    if (s == 0) out[16777216 + ob_s[m] * 16 + j] = acc_;
    lat_s[m * 16 + j] = acc_;
  }
  __syncthreads();
  // ---- ctx = leaky(latent@Wle + ble): full, into hx ----
  for (int i = tid; i < 4096; i += 256) {
    int m = i >> 8, c = i & 255;
    float v = ble[c];
#pragma unroll
    for (int k = 0; k < 16; k++) v = fmaf(lat_s[m * 16 + k], Wle[k * 256 + c], v);
    v = v >= 0.f ? v : 0.01f * v;
    hx[m * LD + c] = f2bf(v);
  }
  __syncthreads();
#pragma unroll
  for (int r = 0; r < 4; r++) creg[r] = bf2f(hx[(q * 4 + r) * LD + s * 64 + w * 16 + n16]);

  // ---- decoder resident weights (reuse reg arrays) ----
  const uint4* wd4 = (const uint4*)wd_p;
  const uint4* wop4 = (const uint4*)wop_p;
#pragma unroll
  for (int f = 0; f < 32; f++) wfh[f] = wd4[((s * 4 + w) * 32 + f) * 64 + lane];
#pragma unroll
  for (int f = 0; f < 8; f++) wfx[f] = wop4[(s * 8 + f) * 64 + lane];
  float bd_r[4];
#pragma unroll
  for (int gt = 0; gt < 4; gt++) bd_r[gt] = bd[gt * 256 + s * 64 + w * 16 + n16];
  float bop_r = bop[s * 16 + n16];
  int orow[4];
#pragma unroll
  for (int r = 0; r < 4; r++) orow[r] = ob_s[q * 4 + r] << 15;

  // wait for partners' ready (they finished reading encoder buffers)
  if (tid < 4 && tid != s) {
    int gdn = 0;
    while (__hip_atomic_load(&dfl[tid], __ATOMIC_ACQUIRE, __HIP_MEMORY_SCOPE_AGENT) < 1 &&
           ++gdn < 300000) {}
  }
  __syncthreads();

  // ================= decoder =================
  for (int d = 0; d < NT_; d++) {
    if (d > 0) {
      if (tid < 4 && tid != s) {
        int gdn = 0;
        while (__hip_atomic_load(&dfl[tid], __ATOMIC_ACQUIRE, __HIP_MEMORY_SCOPE_AGENT) < d + 1 &&
               ++gdn < 300000) {}
      }
      __syncthreads();
      const u64* src = hpg + (u64)(d & 1) * 1024;
#pragma unroll
      for (int e3 = 0; e3 < 3; e3++) {
        int e = e3 * 256 + tid;
        int ss = e >> 8; int sidx = ss + (ss >= s);
        int i = e & 255; int r = i >> 4, c4 = i & 15;
        u64 v = __hip_atomic_load(&src[sidx * 256 + i], __ATOMIC_RELAXED, __HIP_MEMORY_SCOPE_AGENT);
        *(u64*)&hx[r * LD + sidx * 64 + c4 * 4] = v;
      }
    }
    __syncthreads();  // hx = h_d full
    // pred_{d-1} = h_d @ Wop[:, s*16..): compute on all waves, wave0 writes
    f32x4 pacc = splat4(0.f);
#pragma unroll
    for (int ks = 0; ks < 8; ks++) {
      bf16x8 a = *(const bf16x8*)(hxb + n16 * (LD * 2) + ks * 64 + q * 16);
      pacc = __builtin_amdgcn_mfma_f32_16x16x32_bf16(a, asb(wfx[ks]), pacc, 0, 0, 0);
    }
    if (w == 0 && d > 0) {
#pragma unroll
      for (int r = 0; r < 4; r++)
        out[orow[r] + ((d - 1) << 6) + (s << 4) + n16] = pacc[r] + bop_r;
    }
    // z = h_d @ Wd_s + bd_s
    f32x4 acc[4];
#pragma unroll
    for (int gt = 0; gt < 4; gt++) acc[gt] = splat4(bd_r[gt]);
#pragma unroll
    for (int ks = 0; ks < 8; ks++) {
      bf16x8 a = *(const bf16x8*)(hxb + n16 * (LD * 2) + ks * 64 + q * 16);
#pragma unroll
      for (int gt = 0; gt < 4; gt++)
        acc[gt] = __builtin_amdgcn_mfma_f32_16x16x32_bf16(a, asb(wfh[ks * 4 + gt]), acc[gt], 0, 0, 0);
    }
    float nh_s[4];
#pragma unroll
    for (int r = 0; r < 4; r++) {
      float i_ = sigf(acc[0][r]);
      float f_ = sigf(acc[1][r]);
      float g_ = tanhf_(acc[2][r]);
      float o_ = sigf(acc[3][r]);
      float nc = f_ * creg[r] + i_ * g_;
      creg[r] = nc;
      nh_s[r] = o_ * tanhf_(nc);
    }
    __syncthreads();  // reads of hx done
#pragma unroll
    for (int r = 0; r < 4; r++)
      hx[(q * 4 + r) * LD + s * 64 + w * 16 + n16] = f2bf(nh_s[r]);
    __syncthreads();
    {
      u64 v = *(u64*)&hx[xr * LD + s * 64 + xc * 4];
      __hip_atomic_store(&hpg[(u64)((d + 1) & 1) * 1024 + s * 256 + xr * 16 + xc], v,
                         __ATOMIC_RELAXED, __HIP_MEMORY_SCOPE_AGENT);
    }
    __threadfence();
    __syncthreads();
    if (tid == 0) __hip_atomic_fetch_add(&dfl[s], 1, __ATOMIC_RELEASE, __HIP_MEMORY_SCOPE_AGENT);
  }
  // final: h_512 -> recon[:,511]
  if (tid < 4 && tid != s) {
    int gdn = 0;
    while (__hip_atomic_load(&dfl[tid], __ATOMIC_ACQUIRE, __HIP_MEMORY_SCOPE_AGENT) < NT_ + 1 &&
           ++gdn < 300000) {}
  }
  __syncthreads();
  {
    const u64* src = hpg;  // parity 512&1 = 0
#pragma unroll
    for (int e3 = 0; e3 < 3; e3++) {
      int e = e3 * 256 + tid;
      int ss = e >> 8; int sidx = ss + (ss >= s);
      int i = e & 255; int r = i >> 4, c4 = i & 15;
      u64 v = __hip_atomic_load(&src[sidx * 256 + i], __ATOMIC_RELAXED, __HIP_MEMORY_SCOPE_AGENT);
      *(u64*)&hx[r * LD + sidx * 64 + c4 * 4] = v;
    }
  }
  __syncthreads();
  if (w == 0) {
    f32x4 pacc = splat4(0.f);
#pragma unroll
    for (int ks = 0; ks < 8; ks++) {
      bf16x8 a = *(const bf16x8*)(hxb + n16 * (LD * 2) + ks * 64 + q * 16);
      pacc = __builtin_amdgcn_mfma_f32_16x16x32_bf16(a, asb(wfx[ks]), pacc, 0, 0, 0);
    }
#pragma unroll
    for (int r = 0; r < 4; r++)
      out[orow[r] + (511 << 6) + (s << 4) + n16] = pacc[r] + bop_r;
  }
}

// ---------------- host ------------------------------------------------------
// layout (bytes):
//   WHE    [0,        524288)
//   WIE    [524288,  1048576)
//   WD     [1048576, 1572864)
//   WIP    [1572864, 1605632)
//   WOP    [1605632, 1638400)
//   HPUB   [1638400, 2162688)   32 tiles x 16KB  (R2 bug: only 512384 reserved)
//   EFLAG  [2162688, 2163200)
//   DFLAG  [2163200, 2163712)
//   SKEYS  [2163712, 2165760)
#define OFF_WHE 0ull
#define OFF_WIE 524288ull
#define OFF_WD 1048576ull
#define OFF_WIP 1572864ull
#define OFF_WOP 1605632ull
#define OFF_HPUB 1638400ull
#define OFF_EFLAG 2162688ull
#define OFF_DFLAG 2163200ull
#define OFF_SKEYS 2163712ull
#define MIN_WS 2165760ull

extern "C" void kernel_launch(void* const* d_in, const int* in_sizes, int n_in,
                              void* d_out, int out_size, void* d_ws, size_t ws_size,
                              hipStream_t stream) {
  const float* x = (const float*)d_in[0];
  const unsigned char* mask = (const unsigned char*)d_in[1];
  const float* Wip = (const float*)d_in[2];
  const float* bip = (const float*)d_in[3];
  const float* Wie = (const float*)d_in[4];
  const float* Whe = (const float*)d_in[5];
  const float* be = (const float*)d_in[6];
  const float* Wlp = (const float*)d_in[7];
  const float* blp = (const float*)d_in[8];
  const float* Wle = (const float*)d_in[9];
  const float* ble = (const float*)d_in[10];
  const float* Wid = (const float*)d_in[11];
  const float* Whd = (const float*)d_in[12];
  const float* bd = (const float*)d_in[13];
  const float* Wop = (const float*)d_in[14];
  const float* bop = (const float*)d_in[15];
  float* out = (float*)d_out;
  char* ws = (char*)d_ws;

  if (ws_size < MIN_WS) return;

  u16* whe_p = (u16*)(ws + OFF_WHE);
  u16* wie_p = (u16*)(ws + OFF_WIE);
  u16* wd_p = (u16*)(ws + OFF_WD);
  u16* wip_p = (u16*)(ws + OFF_WIP);
  u16* wop_p = (u16*)(ws + OFF_WOP);
  u64* hpub = (u64*)(ws + OFF_HPUB);
  int* eflag = (int*)(ws + OFF_EFLAG);
  int* dflag = (int*)(ws + OFF_DFLAG);
  int* skeys = (int*)(ws + OFF_SKEYS);

  k_pack_g<<<1024, 256, 0, stream>>>(Whe, nullptr, whe_p);
  k_pack_g<<<1024, 256, 0, stream>>>(Wie, nullptr, wie_p);
  k_pack_g<<<1024, 256, 0, stream>>>(Wid, Whd, wd_p);
  k_pack_wip<<<64, 256, 0, stream>>>(Wip, wip_p);
  k_pack_wop<<<64, 256, 0, stream>>>(Wop, wop_p);
  k_lens<<<1, 512, 0, stream>>>(mask, skeys);
  k_sort<<<1, 512, 0, stream>>>(skeys);
  k_zero<<<1, 256, 0, stream>>>(eflag);  // zeroes eflag[128] + dflag[128] (contiguous)

  k_rec2<<<128, 256, 0, stream>>>(x, whe_p, wie_p, wd_p, wip_p, wop_p,
                                  bip, be, Wlp, blp, Wle, ble, bd, bop,
                                  skeys, hpub, eflag, dflag, out);
}

// Round 4
// 3440.371 us; speedup vs baseline: 5.4413x; 3.1185x over previous
//
// LSTM trajectory autoencoder, MI355X gfx950 — R4: relaxed-atomic exchange.
// R3 post-mortem: 10 us/step, all pipes idle; WRITE_SIZE 2x true writes ->
// per-step __threadfence (L2 writeback) + acquire-spin invalidates + RMW flag
// dominate. R4: all cross-block traffic stays sc1 atomics (coherent point);
// ordering via __syncthreads vmcnt-drain + RELAXED flag store; RELAXED polls;
// publish direct from registers; xp and xp@Wie computed before exchange wait.
#include <hip/hip_runtime.h>

typedef unsigned short u16;
typedef unsigned long long u64;
typedef float f32x4 __attribute__((ext_vector_type(4)));
typedef __bf16 bf16x8 __attribute__((ext_vector_type(8)));

#define NT_ 512
#define LD 264   // 16 rows x 264 u16 (8-el pad)
#define SPIN_GUARD 100000

__device__ __forceinline__ u16 f2bf(float f) {
  unsigned u = __builtin_bit_cast(unsigned, f);
  u += 0x7FFFu + ((u >> 16) & 1u);
  return (u16)(u >> 16);
}
__device__ __forceinline__ float bf2f(u16 h) {
  unsigned u = ((unsigned)h) << 16;
  return __builtin_bit_cast(float, u);
}
__device__ __forceinline__ f32x4 splat4(float b) { f32x4 v = {b, b, b, b}; return v; }
__device__ __forceinline__ bf16x8 asb(uint4 v) { return __builtin_bit_cast(bf16x8, v); }
__device__ __forceinline__ float sigf(float v) { return 1.0f / (1.0f + exp2f(-1.44269504f * v)); }
__device__ __forceinline__ float tanhf_(float v) { float e = exp2f(2.88539008f * v); return 1.0f - 2.0f / (e + 1.0f); }

__device__ __forceinline__ u64 gld64(const u64* p) {
  return __hip_atomic_load(p, __ATOMIC_RELAXED, __HIP_MEMORY_SCOPE_AGENT);
}
__device__ __forceinline__ void gst64(u64* p, u64 v) {
  __hip_atomic_store(p, v, __ATOMIC_RELAXED, __HIP_MEMORY_SCOPE_AGENT);
}
__device__ __forceinline__ int gld32(const int* p) {
  return __hip_atomic_load(p, __ATOMIC_RELAXED, __HIP_MEMORY_SCOPE_AGENT);
}
__device__ __forceinline__ void gst32(int* p, int v) {
  __hip_atomic_store(p, v, __ATOMIC_RELAXED, __HIP_MEMORY_SCOPE_AGENT);
}

// ---------------- packing (unchanged from R3) -------------------------------
// gate-weight frag stream: bits  s[17:16] w[15:14] ks[13:11] g[10:9] lane[8:3] j[2:0]
__global__ void k_pack_g(const float* __restrict__ src, const float* __restrict__ src2,
                         u16* __restrict__ dst) {
  int e = blockIdx.x * 256 + threadIdx.x;  // 262144
  int j = e & 7, lane = (e >> 3) & 63, g = (e >> 9) & 3, ks = (e >> 11) & 7;
  int w = (e >> 14) & 3, s = (e >> 16) & 3;
  int k = ks * 32 + ((lane >> 4) << 3) + j;
  int col = g * 256 + s * 64 + w * 16 + (lane & 15);
  float v = src[k * 1024 + col];
  if (src2) v += src2[k * 1024 + col];
  dst[e] = f2bf(v);
}
__global__ void k_pack_wip(const float* __restrict__ Wip, u16* __restrict__ dst) {
  int e = blockIdx.x * 256 + threadIdx.x;  // 16384
  int j = e & 7, lane = (e >> 3) & 63, n = (e >> 9) & 3, ks2 = (e >> 11) & 1, w = (e >> 12) & 3;
  int k = ks2 * 32 + ((lane >> 4) << 3) + j;
  int col = w * 64 + n * 16 + (lane & 15);
  dst[e] = f2bf(Wip[k * 256 + col]);
}
__global__ void k_pack_wop(const float* __restrict__ Wop, u16* __restrict__ dst) {
  int e = blockIdx.x * 256 + threadIdx.x;  // 16384
  int j = e & 7, lane = (e >> 3) & 63, ks = (e >> 9) & 7, s = (e >> 12) & 3;
  int k = ks * 32 + ((lane >> 4) << 3) + j;
  int col = s * 16 + (lane & 15);
  dst[e] = f2bf(Wop[k * 64 + col]);
}

__global__ void k_lens(const unsigned char* __restrict__ mask, int* __restrict__ skeys) {
  int b = threadIdx.x;
  bool u8 = (mask[1] | mask[2] | mask[3]) != 0;
  int s = 0;
  if (u8) { const unsigned char* row = mask + b * NT_; for (int t = 0; t < NT_; t++) s += row[t] ? 1 : 0; }
  else { const int* row = (const int*)mask + b * NT_; for (int t = 0; t < NT_; t++) s += row[t] ? 1 : 0; }
  skeys[b] = s * 1024 + b;
}

__global__ void k_sort(int* __restrict__ skeys) {
  __shared__ int sk[512];
  int tid = threadIdx.x;
  sk[tid] = skeys[tid];
  __syncthreads();
  for (int k = 2; k <= 512; k <<= 1)
    for (int j = k >> 1; j > 0; j >>= 1) {
      int ixj = tid ^ j;
      if (ixj > tid) {
        int a = sk[tid], b = sk[ixj];
        bool up = ((tid & k) == 0);
        if ((a > b) == up) { sk[tid] = b; sk[ixj] = a; }
      }
      __syncthreads();
    }
  skeys[tid] = sk[tid];
}

__global__ void k_zero(int* __restrict__ flags) { flags[threadIdx.x] = 0; }

// ---------------- persistent recurrent kernel ------------------------------
// grid 128 x 256 thr. block b: tile g=(b&7)+((b>>5)<<3), slice s=(b>>3)&3.
// wave w owns h-cols s*64+w*16+[0,16). publish word i=(w*16+n16)*4+q holds
// rows q*4..q*4+3 of col s*64+w*16+n16 (4 bf16 in one u64).
__global__ __launch_bounds__(256, 1) void k_rec3(
    const float* __restrict__ x,
    const u16* __restrict__ whe_p, const u16* __restrict__ wie_p,
    const u16* __restrict__ wd_p, const u16* __restrict__ wip_p,
    const u16* __restrict__ wop_p,
    const float* __restrict__ bip, const float* __restrict__ be,
    const float* __restrict__ Wlp, const float* __restrict__ blp,
    const float* __restrict__ Wle, const float* __restrict__ ble,
    const float* __restrict__ bd, const float* __restrict__ bop,
    const int* __restrict__ skeys,
    u64* __restrict__ hpub, int* __restrict__ eflag, int* __restrict__ dflag,
    float* __restrict__ out) {
  __shared__ __align__(16) u16 hx[16 * LD];
  __shared__ __align__(16) u16 xps[16 * LD];
  __shared__ __align__(16) u16 xbuf[16 * 72];
  __shared__ int ob_s[16], len_s[16];
  __shared__ float lat_s[256];

  const int tid = threadIdx.x;
  const int w = tid >> 6, lane = tid & 63, q = lane >> 4, n16 = lane & 15;
  const int b = blockIdx.x;
  const int g = (b & 7) + ((b >> 5) << 3);
  const int s = (b >> 3) & 3;

  if (tid < 16) {
    int v = skeys[g * 16 + tid];
    ob_s[tid] = v & 1023;
    len_s[tid] = v >> 10;
  }
  for (int i = tid; i < 16 * LD; i += 256) hx[i] = 0;
  __syncthreads();
  int maxlen = 0;
#pragma unroll
  for (int i = 0; i < 16; i++) maxlen = len_s[i] > maxlen ? len_s[i] : maxlen;
  int mylen[4];
#pragma unroll
  for (int r = 0; r < 4; r++) mylen[r] = len_s[q * 4 + r];

  // ---- resident weights ----
  const uint4* whe4 = (const uint4*)whe_p;
  const uint4* wie4 = (const uint4*)wie_p;
  const uint4* wip4 = (const uint4*)wip_p;
  uint4 wfh[32], wfx[32], wipf[8];
#pragma unroll
  for (int f = 0; f < 32; f++) wfh[f] = whe4[((s * 4 + w) * 32 + f) * 64 + lane];
#pragma unroll
  for (int f = 0; f < 32; f++) wfx[f] = wie4[((s * 4 + w) * 32 + f) * 64 + lane];
#pragma unroll
  for (int f = 0; f < 8; f++) wipf[f] = wip4[(w * 8 + f) * 64 + lane];

  float be_r[4], bipr[4];
#pragma unroll
  for (int gt = 0; gt < 4; gt++) be_r[gt] = be[gt * 256 + s * 64 + w * 16 + n16];
#pragma unroll
  for (int n = 0; n < 4; n++) bipr[n] = bip[w * 64 + n * 16 + n16];

  float creg[4], hreg[4];
#pragma unroll
  for (int r = 0; r < 4; r++) { creg[r] = 0.f; hreg[r] = 0.f; }

  const char* hxb = (const char*)hx;
  const char* xpsb = (const char*)xps;
  u64* hpg = hpub + (u64)g * 2048;  // 2 parities x 4 slices x 256 u64
  int* efl = eflag + g * 4;
  int* dfl = dflag + g * 4;
  const int xr = tid >> 4, xc = tid & 15;
  const int pubw = (w * 16 + n16) * 4 + q;             // publish word index
  const int mycol = s * 64 + w * 16 + n16;             // own h column

  // ================= encoder =================
  for (int t = 0; t < maxlen; t++) {
    float4 xv = ((const float4*)x)[((size_t)ob_s[xr] * NT_ + t) * 16 + xc];
    {
      u64 pv = (u64)f2bf(xv.x) | ((u64)f2bf(xv.y) << 16) |
               ((u64)f2bf(xv.z) << 32) | ((u64)f2bf(xv.w) << 48);
      *(u64*)&xbuf[xr * 72 + xc * 4] = pv;
    }
    __syncthreads();  // S1: xbuf ready
    // xp = leaky(x_t @ Wip + bip); wave w computes cols [w*64, w*64+64)
    f32x4 xacc[4];
#pragma unroll
    for (int n = 0; n < 4; n++) xacc[n] = splat4(bipr[n]);
#pragma unroll
    for (int ks2 = 0; ks2 < 2; ks2++) {
      bf16x8 a = *(const bf16x8*)((const char*)xbuf + n16 * 144 + ks2 * 64 + q * 16);
#pragma unroll
      for (int n = 0; n < 4; n++)
        xacc[n] = __builtin_amdgcn_mfma_f32_16x16x32_bf16(a, asb(wipf[ks2 * 4 + n]), xacc[n], 0, 0, 0);
    }
#pragma unroll
    for (int n = 0; n < 4; n++)
#pragma unroll
      for (int r = 0; r < 4; r++) {
        float v = xacc[n][r];
        v = v >= 0.f ? v : 0.01f * v;
        xps[(q * 4 + r) * LD + w * 64 + n * 16 + n16] = f2bf(v);
      }
    __syncthreads();  // S2: xps ready
    // z1 = be + xp @ Wie_s  (no partner data needed -> hides exchange latency)
    f32x4 acc[4];
#pragma unroll
    for (int gt = 0; gt < 4; gt++) acc[gt] = splat4(be_r[gt]);
#pragma unroll
    for (int ks = 0; ks < 8; ks++) {
      bf16x8 a = *(const bf16x8*)(xpsb + n16 * (LD * 2) + ks * 64 + q * 16);
#pragma unroll
      for (int gt = 0; gt < 4; gt++)
        acc[gt] = __builtin_amdgcn_mfma_f32_16x16x32_bf16(a, asb(wfx[ks * 4 + gt]), acc[gt], 0, 0, 0);
    }
    // exchange: wait for partners' h(t), pull into hx
    if (t > 0) {
      if (tid < 4 && tid != s) {
        int gdn = 0;
        while (gld32(&efl[tid]) < t && ++gdn < SPIN_GUARD) {}
      }
      __syncthreads();  // S3: all past spin
      const u64* src = hpg + (u64)(t & 1) * 1024;
#pragma unroll
      for (int e3 = 0; e3 < 3; e3++) {
        int sidx = e3 + (e3 >= s);
        u64 v = gld64(&src[sidx * 256 + tid]);
        int cc = sidx * 64 + (tid >> 2), qq = tid & 3;
#pragma unroll
        for (int r = 0; r < 4; r++) hx[(qq * 4 + r) * LD + cc] = (u16)(v >> (16 * r));
      }
    }
    __syncthreads();  // S4: hx = h(t) full
    // z2 += h @ Whe_s
#pragma unroll
    for (int ks = 0; ks < 8; ks++) {
      bf16x8 a = *(const bf16x8*)(hxb + n16 * (LD * 2) + ks * 64 + q * 16);
#pragma unroll
      for (int gt = 0; gt < 4; gt++)
        acc[gt] = __builtin_amdgcn_mfma_f32_16x16x32_bf16(a, asb(wfh[ks * 4 + gt]), acc[gt], 0, 0, 0);
    }
    // gates (i,f,g,o) + masked carry
    u16 hb[4];
#pragma unroll
    for (int r = 0; r < 4; r++) {
      float i_ = sigf(acc[0][r]);
      float f_ = sigf(acc[1][r]);
      float g_ = tanhf_(acc[2][r]);
      float o_ = sigf(acc[3][r]);
      float nc = f_ * creg[r] + i_ * g_;
      float nh = o_ * tanhf_(nc);
      bool upd = t < mylen[r];
      creg[r] = upd ? nc : creg[r];
      hreg[r] = upd ? nh : hreg[r];
      hb[r] = f2bf(hreg[r]);
    }
    // publish h(t+1) direct from regs (safe: spin proved partners consumed
    // the parity-(t+1) buffer contents h(t-1))
    {
      u64 pv = (u64)hb[0] | ((u64)hb[1] << 16) | ((u64)hb[2] << 32) | ((u64)hb[3] << 48);
      gst64(&hpg[(u64)((t + 1) & 1) * 1024 + s * 256 + pubw], pv);
    }
    __syncthreads();  // S5: all hx reads (z2) done
#pragma unroll
    for (int r = 0; r < 4; r++) hx[(q * 4 + r) * LD + mycol] = hb[r];
    __syncthreads();  // S6: own slice in hx; publish stores drained (vmcnt0)
    if (tid == 0) gst32(&efl[s], t + 1);
  }

  // final exchange: full h(maxlen)
  if (tid < 4 && tid != s) {
    int gdn = 0;
    while (gld32(&efl[tid]) < maxlen && ++gdn < SPIN_GUARD) {}
  }
  __syncthreads();
  {
    const u64* src = hpg + (u64)(maxlen & 1) * 1024;
#pragma unroll
    for (int e3 = 0; e3 < 3; e3++) {
      int sidx = e3 + (e3 >= s);
      u64 v = gld64(&src[sidx * 256 + tid]);
      int cc = sidx * 64 + (tid >> 2), qq = tid & 3;
#pragma unroll
      for (int r = 0; r < 4; r++) hx[(qq * 4 + r) * LD + cc] = (u16)(v >> (16 * r));
    }
  }
  __syncthreads();  // final-exchange loads drained
  if (tid == 0) gst32(&dfl[s], 1);  // ready: done reading encoder buffers

  // ---- latent (redundant per cluster; slice 0 writes) ----
  {
    int m = tid >> 4, j = tid & 15;
    float acc_ = blp[j];
    for (int k = 0; k < 256; k++) acc_ = fmaf(bf2f(hx[m * LD + k]), Wlp[k * 16 + j], acc_);
    if (s == 0) out[16777216 + ob_s[m] * 16 + j] = acc_;
    lat_s[m * 16 + j] = acc_;
  }
  __syncthreads();
  // ---- ctx = leaky(latent@Wle + ble) -> hx (full) ----
  for (int i = tid; i < 4096; i += 256) {
    int m = i >> 8, c = i & 255;
    float v = ble[c];
#pragma unroll
    for (int k = 0; k < 16; k++) v = fmaf(lat_s[m * 16 + k], Wle[k * 256 + c], v);
    v = v >= 0.f ? v : 0.01f * v;
    hx[m * LD + c] = f2bf(v);
  }
  __syncthreads();
#pragma unroll
  for (int r = 0; r < 4; r++) {
    hreg[r] = bf2f(hx[(q * 4 + r) * LD + mycol]);
    creg[r] = hreg[r];
  }

  // ---- decoder resident weights ----
  const uint4* wd4 = (const uint4*)wd_p;
  const uint4* wop4 = (const uint4*)wop_p;
#pragma unroll
  for (int f = 0; f < 32; f++) wfh[f] = wd4[((s * 4 + w) * 32 + f) * 64 + lane];
#pragma unroll
  for (int f = 0; f < 8; f++) wfx[f] = wop4[(s * 8 + f) * 64 + lane];
  float bd_r[4];
#pragma unroll
  for (int gt = 0; gt < 4; gt++) bd_r[gt] = bd[gt * 256 + s * 64 + w * 16 + n16];
  float bop_r = bop[s * 16 + n16];
  int orow[4];
#pragma unroll
  for (int r = 0; r < 4; r++) orow[r] = ob_s[q * 4 + r] << 15;

  // wait partners ready (they finished reading encoder buffers)
  if (tid < 4 && tid != s) {
    int gdn = 0;
    while (gld32(&dfl[tid]) < 1 && ++gdn < SPIN_GUARD) {}
  }
  __syncthreads();

  // ================= decoder =================
  for (int d = 0; d < NT_; d++) {
    if (d > 0) {
      if (tid < 4 && tid != s) {
        int gdn = 0;
        while (gld32(&dfl[tid]) < d + 1 && ++gdn < SPIN_GUARD) {}
      }
      __syncthreads();  // A: all past spin
      const u64* src = hpg + (u64)(d & 1) * 1024;
#pragma unroll
      for (int e3 = 0; e3 < 3; e3++) {
        int sidx = e3 + (e3 >= s);
        u64 v = gld64(&src[sidx * 256 + tid]);
        int cc = sidx * 64 + (tid >> 2), qq = tid & 3;
#pragma unroll
        for (int r = 0; r < 4; r++) hx[(qq * 4 + r) * LD + cc] = (u16)(v >> (16 * r));
      }
    }
    __syncthreads();  // B: hx = h(d) full
    // pred_{d-1} = h_d @ Wop cols s*16.. (computed on all waves, w0 writes)
    f32x4 pacc = splat4(0.f);
#pragma unroll
    for (int ks = 0; ks < 8; ks++) {
      bf16x8 a = *(const bf16x8*)(hxb + n16 * (LD * 2) + ks * 64 + q * 16);
      pacc = __builtin_amdgcn_mfma_f32_16x16x32_bf16(a, asb(wfx[ks]), pacc, 0, 0, 0);
    }
    if (w == 0 && d > 0) {
#pragma unroll
      for (int r = 0; r < 4; r++)
        out[orow[r] + ((d - 1) << 6) + (s << 4) + n16] = pacc[r] + bop_r;
    }
    // z = h_d @ Wd_s + bd_s
    f32x4 acc[4];
#pragma unroll
    for (int gt = 0; gt < 4; gt++) acc[gt] = splat4(bd_r[gt]);
#pragma unroll
    for (int ks = 0; ks < 8; ks++) {
      bf16x8 a = *(const bf16x8*)(hxb + n16 * (LD * 2) + ks * 64 + q * 16);
#pragma unroll
      for (int gt = 0; gt < 4; gt++)
        acc[gt] = __builtin_amdgcn_mfma_f32_16x16x32_bf16(a, asb(wfh[ks * 4 + gt]), acc[gt], 0, 0, 0);
    }
    u16 hb[4];
#pragma unroll
    for (int r = 0; r < 4; r++) {
      float i_ = sigf(acc[0][r]);
      float f_ = sigf(acc[1][r]);
      float g_ = tanhf_(acc[2][r]);
      float o_ = sigf(acc[3][r]);
      float nc = f_ * creg[r] + i_ * g_;
      creg[r] = nc;
      hreg[r] = o_ * tanhf_(nc);
      hb[r] = f2bf(hreg[r]);
    }
    {
      u64 pv = (u64)hb[0] | ((u64)hb[1] << 16) | ((u64)hb[2] << 32) | ((u64)hb[3] << 48);
      gst64(&hpg[(u64)((d + 1) & 1) * 1024 + s * 256 + pubw], pv);
    }
    __syncthreads();  // C: hx reads done
#pragma unroll
    for (int r = 0; r < 4; r++) hx[(q * 4 + r) * LD + mycol] = hb[r];
    __syncthreads();  // D: hx updated; publish drained
    if (tid == 0) gst32(&dfl[s], d + 2);
  }
  // final: h(512) -> recon[:,511]
  if (tid < 4 && tid != s) {
    int gdn = 0;
    while (gld32(&dfl[tid]) < NT_ + 1 && ++gdn < SPIN_GUARD) {}
  }
  __syncthreads();
  {
    const u64* src = hpg;  // parity 512&1 = 0
#pragma unroll
    for (int e3 = 0; e3 < 3; e3++) {
      int sidx = e3 + (e3 >= s);
      u64 v = gld64(&src[sidx * 256 + tid]);
      int cc = sidx * 64 + (tid >> 2), qq = tid & 3;
#pragma unroll
      for (int r = 0; r < 4; r++) hx[(qq * 4 + r) * LD + cc] = (u16)(v >> (16 * r));
    }
  }
  __syncthreads();
  if (w == 0) {
    f32x4 pacc = splat4(0.f);
#pragma unroll
    for (int ks = 0; ks < 8; ks++) {
      bf16x8 a = *(const bf16x8*)(hxb + n16 * (LD * 2) + ks * 64 + q * 16);
      pacc = __builtin_amdgcn_mfma_f32_16x16x32_bf16(a, asb(wfx[ks]), pacc, 0, 0, 0);
    }
#pragma unroll
    for (int r = 0; r < 4; r++)
      out[orow[r] + (511 << 6) + (s << 4) + n16] = pacc[r] + bop_r;
  }
}

// ---------------- host ------------------------------------------------------
// layout (bytes): WHE 0 | WIE 524288 | WD 1048576 | WIP 1572864 | WOP 1605632 |
// HPUB 1638400..2162688 (32 tiles x 16KB) | EFLAG | DFLAG | SKEYS
#define OFF_WHE 0ull
#define OFF_WIE 524288ull
#define OFF_WD 1048576ull
#define OFF_WIP 1572864ull
#define OFF_WOP 1605632ull
#define OFF_HPUB 1638400ull
#define OFF_EFLAG 2162688ull
#define OFF_DFLAG 2163200ull
#define OFF_SKEYS 2163712ull
#define MIN_WS 2165760ull

extern "C" void kernel_launch(void* const* d_in, const int* in_sizes, int n_in,
                              void* d_out, int out_size, void* d_ws, size_t ws_size,
                              hipStream_t stream) {
  const float* x = (const float*)d_in[0];
  const unsigned char* mask = (const unsigned char*)d_in[1];
  const float* Wip = (const float*)d_in[2];
  const float* bip = (const float*)d_in[3];
  const float* Wie = (const float*)d_in[4];
  const float* Whe = (const float*)d_in[5];
  const float* be = (const float*)d_in[6];
  const float* Wlp = (const float*)d_in[7];
  const float* blp = (const float*)d_in[8];
  const float* Wle = (const float*)d_in[9];
  const float* ble = (const float*)d_in[10];
  const float* Wid = (const float*)d_in[11];
  const float* Whd = (const float*)d_in[12];
  const float* bd = (const float*)d_in[13];
  const float* Wop = (const float*)d_in[14];
  const float* bop = (const float*)d_in[15];
  float* out = (float*)d_out;
  char* ws = (char*)d_ws;

  if (ws_size < MIN_WS) return;

  u16* whe_p = (u16*)(ws + OFF_WHE);
  u16* wie_p = (u16*)(ws + OFF_WIE);
  u16* wd_p = (u16*)(ws + OFF_WD);
  u16* wip_p = (u16*)(ws + OFF_WIP);
  u16* wop_p = (u16*)(ws + OFF_WOP);
  u64* hpub = (u64*)(ws + OFF_HPUB);
  int* eflag = (int*)(ws + OFF_EFLAG);
  int* dflag = (int*)(ws + OFF_DFLAG);
  int* skeys = (int*)(ws + OFF_SKEYS);

  k_pack_g<<<1024, 256, 0, stream>>>(Whe, nullptr, whe_p);
  k_pack_g<<<1024, 256, 0, stream>>>(Wie, nullptr, wie_p);
  k_pack_g<<<1024, 256, 0, stream>>>(Wid, Whd, wd_p);
  k_pack_wip<<<64, 256, 0, stream>>>(Wip, wip_p);
  k_pack_wop<<<64, 256, 0, stream>>>(Wop, wop_p);
  k_lens<<<1, 512, 0, stream>>>(mask, skeys);
  k_sort<<<1, 512, 0, stream>>>(skeys);
  k_zero<<<1, 256, 0, stream>>>(eflag);  // zeroes eflag[128]+dflag[128]

  k_rec3<<<128, 256, 0, stream>>>(x, whe_p, wie_p, wd_p, wip_p, wop_p,
                                  bip, be, Wlp, blp, Wle, ble, bd, bop,
                                  skeys, hpub, eflag, dflag, out);
}